// Round 8
// baseline (233.333 us; speedup 1.0000x reference)
//
#include <hip/hip_runtime.h>
#include <math.h>

// Problem constants (fixed shapes)
#define DIM    4096
#define NH     32
#define NKV    8
#define HD     128
#define BS     16
#define KVLEN  4096
#define LASTPOS 4095
#define QKV_COLS 6144   // 4096 q + 1024 k + 1024 v
#define NKC    64       // k-chunks for split-K projections
#define TCHUNK 64       // kv rows per attn block
#define NCHK   64       // kv chunks (4096/64)
#define NSTG   8        // stages per block (8 rows each)

typedef float f32x4 __attribute__((ext_vector_type(4)));

// ws layout (floats):
//   qkv   : [16][6144]                  @ 0         (98304)
//   attn  : [16][4096]                  @ 98304     (65536)
//   part  : [16][64][8][4][132]         @ 163840    (4325376)
//   pq    : [64][16][6144]              @ 4489216   (6291456)
//   pw    : [64][16][4096]              @ 10780672  (4194304)  end 14974976 (~60MB)
#define WS_QKV   0
#define WS_ATTN  98304
#define WS_PART  163840
#define WS_PQ    4489216
#define WS_PW    10780672

// ---------------------------------------------------------------------------
// K1a: qkv partials. block: 256 thr, 2 cols/thread (512 cols); grid (12, 64).
// ---------------------------------------------------------------------------
__global__ __launch_bounds__(256) void qkv_projA(
    const float* __restrict__ x, const float* __restrict__ wq,
    const float* __restrict__ wk, const float* __restrict__ wv,
    float* __restrict__ pq) {
  __shared__ float xs[16 * 64];
  const int tid = threadIdx.x;
  const int col = (blockIdx.x * 256 + tid) * 2;   // block-uniform matrix select
  const int kc = blockIdx.y;
  const int k0 = kc * 64;

  for (int i = tid; i < 1024; i += 256) {
    int b = i >> 6, k = i & 63;
    xs[i] = x[b * DIM + k0 + k];
  }
  __syncthreads();

  const float* w;
  int wstride, wcol;
  if (col < 4096)      { w = wq; wstride = 4096; wcol = col; }
  else if (col < 5120) { w = wk; wstride = 1024; wcol = col - 4096; }
  else                 { w = wv; wstride = 1024; wcol = col - 5120; }
  const float* wp = w + (size_t)k0 * wstride + wcol;

  float acc0[16], acc1[16];
#pragma unroll
  for (int b = 0; b < 16; ++b) { acc0[b] = 0.f; acc1[b] = 0.f; }

#pragma unroll 2
  for (int k = 0; k < 64; k += 4) {
    float2 w0 = *(const float2*)(wp + (size_t)(k + 0) * wstride);
    float2 w1 = *(const float2*)(wp + (size_t)(k + 1) * wstride);
    float2 w2 = *(const float2*)(wp + (size_t)(k + 2) * wstride);
    float2 w3 = *(const float2*)(wp + (size_t)(k + 3) * wstride);
#pragma unroll
    for (int b = 0; b < 16; ++b) {
      float4 xb = *(const float4*)(&xs[b * 64 + k]);
      acc0[b] += xb.x * w0.x + xb.y * w1.x + xb.z * w2.x + xb.w * w3.x;
      acc1[b] += xb.x * w0.y + xb.y * w1.y + xb.z * w2.y + xb.w * w3.y;
    }
  }
#pragma unroll
  for (int b = 0; b < 16; ++b) {
    *(float2*)(&pq[((size_t)kc * 16 + b) * QKV_COLS + col]) = make_float2(acc0[b], acc1[b]);
  }
}

// ---------------------------------------------------------------------------
// K1b: reduce 64 qkv partials + fused RoPE (+ q scale).
// ---------------------------------------------------------------------------
__global__ __launch_bounds__(256) void qkv_projB(
    const float* __restrict__ pq, float* __restrict__ qkv,
    const float* __restrict__ fc, const float* __restrict__ fs) {
  int t = blockIdx.x * 256 + threadIdx.x;       // 0..49151
  int b = t / 3072, pr = t % 3072;
  int col = 2 * pr;
  float e = 0.f, o = 0.f;
#pragma unroll 8
  for (int kc = 0; kc < NKC; ++kc) {
    float2 v = *(const float2*)(&pq[((size_t)kc * 16 + b) * QKV_COLS + col]);
    e += v.x; o += v.y;
  }
  float re = e, im = o;
  if (col < 5120) {  // q or k: rope
    int i = (col & 127) >> 1;
    float c = fc[i], s = fs[i];
    float scale = (col < 4096) ? 0.08838834764831845f : 1.0f;
    re = (e * c - o * s) * scale;
    im = (e * s + o * c) * scale;
  }
  *(float2*)(&qkv[b * QKV_COLS + col]) = make_float2(re, im);
}

// ---------------------------------------------------------------------------
// K3: attention, contiguous-streaming. block = (b, 64-row chunk), 512 thr =
// 8 waves; wave w owns kv-head g=w. Per 8-row stage the block loads
// cache_k[b][t..t+8][*][*] (32 KB flat contiguous) + same for V into LDS
// (T14 async split: issue loads -> compute current -> barrier -> ds_write ->
// barrier). Per-wave online flash softmax in registers.
// Scores (from LDS): 16-lane group per row, lane ql covers d=[ql*4,+4) and
//   [64+ql*4,+4); xor(1,2,4,8) reduce; lane keeps score(row it*4+p, head ql&3).
// PV (from LDS): half-wave owns a row, lane covers d=dq*4..+4; P via shfl.
// ---------------------------------------------------------------------------
__global__ __launch_bounds__(512, 4) void attn_partial(
    const float* __restrict__ cache_k, const float* __restrict__ cache_v,
    const float* __restrict__ qkv, float* __restrict__ part) {
  __shared__ float ks[8192];   // [row][g*128+d] flat, 32 KB
  __shared__ float vs[8192];   // 32 KB
  const int tid = threadIdx.x;
  const int w = tid >> 6, lane = tid & 63;
  const int p = lane >> 4, ql = lane & 15;
  const int hsel = ql & 3;
  const int chunk = blockIdx.x & (NCHK - 1);
  const int b = blockIdx.x >> 6;
  const int t0 = chunk * TCHUNK;

  // Q fragments for g = w: head h, d = [ql*4,+4) and [64+ql*4,+4)
  const float* qbase = qkv + b * QKV_COLS + w * 512;
  f32x4 qA[4], qB[4];
#pragma unroll
  for (int h = 0; h < 4; ++h) {
    qA[h] = *(const f32x4*)(qbase + h * 128 + ql * 4);
    qB[h] = *(const f32x4*)(qbase + h * 128 + 64 + ql * 4);
  }

  const float* kroot = cache_k + (size_t)b * 4096 * 1024;
  const float* vroot = cache_v + (size_t)b * 4096 * 1024;
  const float* xk = qkv + b * QKV_COLS + 4096;   // [g*128+d] contiguous
  const float* xv = qkv + b * QKV_COLS + 5120;

  float m = -1e30f, l = 0.f;
  f32x4 acc[4];
#pragma unroll
  for (int h = 0; h < 4; ++h) acc[h] = (f32x4)(0.f);

  f32x4 kreg[4], vreg[4];

  // ---- prologue: load stage 0 and stage it in LDS ----
#pragma unroll
  for (int j = 0; j < 4; ++j) {
    int flat = j * 2048 + tid * 4;
    int row = flat >> 10, col = flat & 1023;
    int t = t0 + row;
    kreg[j] = *(const f32x4*)((t == LASTPOS) ? (xk + col) : (kroot + (size_t)t * 1024 + col));
    vreg[j] = *(const f32x4*)((t == LASTPOS) ? (xv + col) : (vroot + (size_t)t * 1024 + col));
  }
#pragma unroll
  for (int j = 0; j < 4; ++j) {
    int flat = j * 2048 + tid * 4;
    *(f32x4*)(&ks[flat]) = kreg[j];
    *(f32x4*)(&vs[flat]) = vreg[j];
  }
  __syncthreads();

  const int h2 = lane >> 5, dq = lane & 31;

  for (int s = 0; s < NSTG; ++s) {
    // issue next stage's global loads (hidden under compute)
    if (s + 1 < NSTG) {
#pragma unroll
      for (int j = 0; j < 4; ++j) {
        int flat = j * 2048 + tid * 4;
        int row = flat >> 10, col = flat & 1023;
        int t = t0 + (s + 1) * 8 + row;
        kreg[j] = *(const f32x4*)((t == LASTPOS) ? (xk + col) : (kroot + (size_t)t * 1024 + col));
        vreg[j] = *(const f32x4*)((t == LASTPOS) ? (xv + col) : (vroot + (size_t)t * 1024 + col));
      }
    }

    // ---- scores for this stage's 8 rows (head hsel) ----
    float sv[2];
#pragma unroll
    for (int it = 0; it < 2; ++it) {
      int row = it * 4 + p;
      f32x4 k0 = *(const f32x4*)(&ks[row * 1024 + w * 128 + ql * 4]);
      f32x4 k1 = *(const f32x4*)(&ks[row * 1024 + w * 128 + 64 + ql * 4]);
      float s4[4];
#pragma unroll
      for (int h = 0; h < 4; ++h) {
        s4[h] = k0[0]*qA[h][0] + k0[1]*qA[h][1] + k0[2]*qA[h][2] + k0[3]*qA[h][3]
              + k1[0]*qB[h][0] + k1[1]*qB[h][1] + k1[2]*qB[h][2] + k1[3]*qB[h][3];
      }
#pragma unroll
      for (int off = 1; off < 16; off <<= 1) {
#pragma unroll
        for (int h = 0; h < 4; ++h) s4[h] += __shfl_xor(s4[h], off);
      }
      float v = s4[0];
      if (hsel == 1) v = s4[1];
      if (hsel == 2) v = s4[2];
      if (hsel == 3) v = s4[3];
      sv[it] = v;
    }

    // ---- online softmax update ----
    float ms = fmaxf(sv[0], sv[1]);
    ms = fmaxf(ms, __shfl_xor(ms, 16));
    ms = fmaxf(ms, __shfl_xor(ms, 32));
    float mnew = fmaxf(m, ms);
    float f = __expf(m - mnew);
    m = mnew;
    sv[0] = __expf(sv[0] - m);
    sv[1] = __expf(sv[1] - m);
    float ssum = sv[0] + sv[1];
    ssum += __shfl_xor(ssum, 16);
    ssum += __shfl_xor(ssum, 32);
    l = l * f + ssum;
    float f0 = __shfl(f, 0), f1 = __shfl(f, 1), f2 = __shfl(f, 2), f3 = __shfl(f, 3);
    acc[0] *= f0; acc[1] *= f1; acc[2] *= f2; acc[3] *= f3;

    // ---- PV for this stage's 8 rows ----
#pragma unroll
    for (int jj = 0; jj < 4; ++jj) {
      int lr = jj * 2 + h2;
      f32x4 vv = *(const f32x4*)(&vs[lr * 1024 + w * 128 + dq * 4]);
      float sreg = (lr >> 2) ? sv[1] : sv[0];
      int srcb = (lr & 3) << 4;
      float p0 = __shfl(sreg, srcb + 0);
      float p1 = __shfl(sreg, srcb + 1);
      float p2 = __shfl(sreg, srcb + 2);
      float p3 = __shfl(sreg, srcb + 3);
      acc[0] += p0 * vv;
      acc[1] += p1 * vv;
      acc[2] += p2 * vv;
      acc[3] += p3 * vv;
    }

    __syncthreads();
    if (s + 1 < NSTG) {
#pragma unroll
      for (int j = 0; j < 4; ++j) {
        int flat = j * 2048 + tid * 4;
        *(f32x4*)(&ks[flat]) = kreg[j];
        *(f32x4*)(&vs[flat]) = vreg[j];
      }
      __syncthreads();
    }
  }

  // ---- write per-(block, g=w, h) partials ----
#pragma unroll
  for (int h = 0; h < 4; ++h) {
    acc[h][0] += __shfl_xor(acc[h][0], 32);
    acc[h][1] += __shfl_xor(acc[h][1], 32);
    acc[h][2] += __shfl_xor(acc[h][2], 32);
    acc[h][3] += __shfl_xor(acc[h][3], 32);
  }
  size_t pbase = ((size_t)(blockIdx.x) * 8 + w) * 4;
  if (lane < 32) {
#pragma unroll
    for (int h = 0; h < 4; ++h)
      *(f32x4*)(&part[(pbase + h) * 132 + dq * 4]) = acc[h];
  }
  if (lane < 4) {
    part[(pbase + lane) * 132 + 128] = m;
    part[(pbase + lane) * 132 + 129] = l;
  }
}

// ---------------------------------------------------------------------------
// K4: merge 64 chunk-partials per (b,g,h,d) -> attn_out. 65536 threads.
// Online merge (running M / num / den).
// ---------------------------------------------------------------------------
__global__ __launch_bounds__(256) void attn_combine(
    const float* __restrict__ part, float* __restrict__ attn_out) {
  int t = blockIdx.x * 256 + threadIdx.x;   // 0..65535
  int d = t & 127, h = (t >> 7) & 3, g = (t >> 9) & 7, b = t >> 12;
  float M = -1e30f, num = 0.f, den = 0.f;
  for (int c = 0; c < NCHK; ++c) {
    const float* pr = part + ((size_t)((b * NCHK + c) * 8 + g) * 4 + h) * 132;
    float mc = pr[128];
    float Mn = fmaxf(M, mc);
    float fo = __expf(M - Mn);
    float fcur = __expf(mc - Mn);
    num = num * fo + fcur * pr[d];
    den = den * fo + fcur * pr[129];
    M = Mn;
  }
  attn_out[b * DIM + (g * 4 + h) * 128 + d] = num / den;
}

// ---------------------------------------------------------------------------
// K5a: wo partials. block: 256 thr, 2 cols/thread (512 cols); grid (8, 64).
// ---------------------------------------------------------------------------
__global__ __launch_bounds__(256) void out_projA(
    const float* __restrict__ attn, const float* __restrict__ wo,
    float* __restrict__ pw) {
  __shared__ float xs[16 * 64];
  const int tid = threadIdx.x;
  const int col = (blockIdx.x * 256 + tid) * 2;  // 0..4094
  const int kc = blockIdx.y;
  const int k0 = kc * 64;

  for (int i = tid; i < 1024; i += 256) {
    int b = i >> 6, k = i & 63;
    xs[i] = attn[b * DIM + k0 + k];
  }
  __syncthreads();

  const float* wp = wo + (size_t)k0 * 4096 + col;
  float acc0[16], acc1[16];
#pragma unroll
  for (int b = 0; b < 16; ++b) { acc0[b] = 0.f; acc1[b] = 0.f; }

#pragma unroll 2
  for (int k = 0; k < 64; k += 4) {
    float2 w0 = *(const float2*)(wp + (size_t)(k + 0) * 4096);
    float2 w1 = *(const float2*)(wp + (size_t)(k + 1) * 4096);
    float2 w2 = *(const float2*)(wp + (size_t)(k + 2) * 4096);
    float2 w3 = *(const float2*)(wp + (size_t)(k + 3) * 4096);
#pragma unroll
    for (int b = 0; b < 16; ++b) {
      float4 xb = *(const float4*)(&xs[b * 64 + k]);
      acc0[b] += xb.x * w0.x + xb.y * w1.x + xb.z * w2.x + xb.w * w3.x;
      acc1[b] += xb.x * w0.y + xb.y * w1.y + xb.z * w2.y + xb.w * w3.y;
    }
  }
#pragma unroll
  for (int b = 0; b < 16; ++b) {
    *(float2*)(&pw[((size_t)kc * 16 + b) * DIM + col]) = make_float2(acc0[b], acc1[b]);
  }
}

// ---------------------------------------------------------------------------
// K5b: reduce 64 wo partials -> d_out.
// ---------------------------------------------------------------------------
__global__ __launch_bounds__(256) void out_projB(
    const float* __restrict__ pw, float* __restrict__ out) {
  int t = blockIdx.x * 256 + threadIdx.x;  // 65536
  int b = t >> 12, col = t & 4095;
  float sum = 0.f;
#pragma unroll 8
  for (int kc = 0; kc < NKC; ++kc)
    sum += pw[((size_t)kc * 16 + b) * DIM + col];
  out[b * DIM + col] = sum;
}

// ---------------------------------------------------------------------------
extern "C" void kernel_launch(void* const* d_in, const int* in_sizes, int n_in,
                              void* d_out, int out_size, void* d_ws, size_t ws_size,
                              hipStream_t stream) {
  const float* x  = (const float*)d_in[0];
  const float* wq = (const float*)d_in[1];
  const float* wk = (const float*)d_in[2];
  const float* wv = (const float*)d_in[3];
  const float* wo = (const float*)d_in[4];
  const float* ck = (const float*)d_in[5];
  const float* cv = (const float*)d_in[6];
  const float* fc = (const float*)d_in[7];
  const float* fs = (const float*)d_in[8];

  float* ws_f  = (float*)d_ws;
  float* qkv   = ws_f + WS_QKV;
  float* attn  = ws_f + WS_ATTN;
  float* part  = ws_f + WS_PART;
  float* pq    = ws_f + WS_PQ;
  float* pw    = ws_f + WS_PW;
  float* out   = (float*)d_out;

  qkv_projA<<<dim3(12, NKC), 256, 0, stream>>>(x, wq, wk, wv, pq);
  qkv_projB<<<192, 256, 0, stream>>>(pq, qkv, fc, fs);
  attn_partial<<<16 * NCHK, 512, 0, stream>>>(ck, cv, qkv, part);
  attn_combine<<<256, 256, 0, stream>>>(part, attn);
  out_projA<<<dim3(8, NKC), 256, 0, stream>>>(attn, wo, pw);
  out_projB<<<256, 256, 0, stream>>>(pw, out);
}

// Round 9
// 200.334 us; speedup vs baseline: 1.1647x; 1.1647x over previous
//
#include <hip/hip_runtime.h>
#include <math.h>

// Problem constants (fixed shapes)
#define DIM    4096
#define NH     32
#define NKV    8
#define HD     128
#define BS     16
#define KVLEN  4096
#define LASTPOS 4095
#define QKV_COLS 6144   // 4096 q + 1024 k + 1024 v
#define NKC    64       // k-chunks for split-K projections
#define ACHUNK 256      // kv rows per attn block
#define NACH   16       // attn chunks (4096/256)

typedef float f32x4 __attribute__((ext_vector_type(4)));

// ws layout (floats):
//   qkv   : [16][6144]                @ 0        (98304)
//   attn  : [16][4096]                @ 98304    (65536)
//   pbuf  : [16][8][16][4][256]       @ 163840   (2097152)  unnormalized probs
//   mlbuf : [16][8][16][4][2]         @ 2260992  (16384)
//   part  : [16][8][16][4][128]       @ 2277376  (1048576)
//   pq    : [64][16][6144]            @ 3325952  (6291456)
//   pw    : [64][16][4096]            @ 9617408  (4194304)  end 13811712 (~55MB)
#define WS_QKV   0
#define WS_ATTN  98304
#define WS_PBUF  163840
#define WS_MLBUF 2260992
#define WS_PART  2277376
#define WS_PQ    3325952
#define WS_PW    9617408

// ---------------------------------------------------------------------------
// K1a: qkv partials. block: 256 thr, 2 cols/thread (512 cols); grid (12, 64).
// ---------------------------------------------------------------------------
__global__ __launch_bounds__(256) void qkv_projA(
    const float* __restrict__ x, const float* __restrict__ wq,
    const float* __restrict__ wk, const float* __restrict__ wv,
    float* __restrict__ pq) {
  __shared__ float xs[16 * 64];
  const int tid = threadIdx.x;
  const int col = (blockIdx.x * 256 + tid) * 2;   // block-uniform matrix select
  const int kc = blockIdx.y;
  const int k0 = kc * 64;

  for (int i = tid; i < 1024; i += 256) {
    int b = i >> 6, k = i & 63;
    xs[i] = x[b * DIM + k0 + k];
  }
  __syncthreads();

  const float* w;
  int wstride, wcol;
  if (col < 4096)      { w = wq; wstride = 4096; wcol = col; }
  else if (col < 5120) { w = wk; wstride = 1024; wcol = col - 4096; }
  else                 { w = wv; wstride = 1024; wcol = col - 5120; }
  const float* wp = w + (size_t)k0 * wstride + wcol;

  float acc0[16], acc1[16];
#pragma unroll
  for (int b = 0; b < 16; ++b) { acc0[b] = 0.f; acc1[b] = 0.f; }

#pragma unroll 2
  for (int k = 0; k < 64; k += 4) {
    float2 w0 = *(const float2*)(wp + (size_t)(k + 0) * wstride);
    float2 w1 = *(const float2*)(wp + (size_t)(k + 1) * wstride);
    float2 w2 = *(const float2*)(wp + (size_t)(k + 2) * wstride);
    float2 w3 = *(const float2*)(wp + (size_t)(k + 3) * wstride);
#pragma unroll
    for (int b = 0; b < 16; ++b) {
      float4 xb = *(const float4*)(&xs[b * 64 + k]);
      acc0[b] += xb.x * w0.x + xb.y * w1.x + xb.z * w2.x + xb.w * w3.x;
      acc1[b] += xb.x * w0.y + xb.y * w1.y + xb.z * w2.y + xb.w * w3.y;
    }
  }
#pragma unroll
  for (int b = 0; b < 16; ++b) {
    *(float2*)(&pq[((size_t)kc * 16 + b) * QKV_COLS + col]) = make_float2(acc0[b], acc1[b]);
  }
}

// ---------------------------------------------------------------------------
// K1b: reduce 64 qkv partials + fused RoPE (+ q scale).
// ---------------------------------------------------------------------------
__global__ __launch_bounds__(256) void qkv_projB(
    const float* __restrict__ pq, float* __restrict__ qkv,
    const float* __restrict__ fc, const float* __restrict__ fs) {
  int t = blockIdx.x * 256 + threadIdx.x;       // 0..49151
  int b = t / 3072, pr = t % 3072;
  int col = 2 * pr;
  float e = 0.f, o = 0.f;
#pragma unroll 8
  for (int kc = 0; kc < NKC; ++kc) {
    float2 v = *(const float2*)(&pq[((size_t)kc * 16 + b) * QKV_COLS + col]);
    e += v.x; o += v.y;
  }
  float re = e, im = o;
  if (col < 5120) {  // q or k: rope
    int i = (col & 127) >> 1;
    float c = fc[i], s = fs[i];
    float scale = (col < 4096) ? 0.08838834764831845f : 1.0f;
    re = (e * c - o * s) * scale;
    im = (e * s + o * c) * scale;
  }
  *(float2*)(&qkv[b * QKV_COLS + col]) = make_float2(re, im);
}

// ---------------------------------------------------------------------------
// K3a: score pass — pure K streaming. block = (b, g, 256-row chunk), 512 thr
// = 8 waves; wave w owns rows [w*32, w*32+32). 16-lane group per row (4 rows
// in parallel), lane ql covers d=[ql*4,+4) and [64+ql*4,+4); xor(1,2,4,8)
// reduce; lane keeps sv[it] = score(row it*4+p, head ql&3). Block softmax via
// tiny LDS (2 barriers), writes unnormalized probs + (m,l) per chunk.
// ---------------------------------------------------------------------------
__global__ __launch_bounds__(512) void attn_score(
    const float* __restrict__ cache_k, const float* __restrict__ qkv,
    float* __restrict__ pbuf, float* __restrict__ mlbuf) {
  __shared__ float red[8][4][2];                // [wave][head][{m,l}]
  const int tid = threadIdx.x;
  const int w = tid >> 6, lane = tid & 63;
  const int p = lane >> 4, ql = lane & 15, hsel = ql & 3;
  const int c = blockIdx.x & (NACH - 1);
  const int g = (blockIdx.x >> 4) & 7;
  const int b = blockIdx.x >> 7;
  const int t0 = c * ACHUNK;

  const float* qbase = qkv + b * QKV_COLS + g * 512;
  f32x4 qA[4], qB[4];
#pragma unroll
  for (int h = 0; h < 4; ++h) {
    qA[h] = *(const f32x4*)(qbase + h * 128 + ql * 4);
    qB[h] = *(const f32x4*)(qbase + h * 128 + 64 + ql * 4);
  }

  const float* kbase = cache_k + ((size_t)b * 4096 * 8 + g) * 128;
  const float* xk    = qkv + b * QKV_COLS + 4096 + g * 128;

  float sv[8];
#pragma unroll
  for (int it = 0; it < 8; ++it) {
    int r = w * 32 + it * 4 + p;
    int t = t0 + r;
    const float* krow = (t == LASTPOS) ? xk : (kbase + (size_t)t * 1024);
    f32x4 k0 = *(const f32x4*)(krow + ql * 4);
    f32x4 k1 = *(const f32x4*)(krow + 64 + ql * 4);
    float s4[4];
#pragma unroll
    for (int h = 0; h < 4; ++h) {
      s4[h] = k0[0]*qA[h][0] + k0[1]*qA[h][1] + k0[2]*qA[h][2] + k0[3]*qA[h][3]
            + k1[0]*qB[h][0] + k1[1]*qB[h][1] + k1[2]*qB[h][2] + k1[3]*qB[h][3];
    }
#pragma unroll
    for (int off = 1; off < 16; off <<= 1) {
#pragma unroll
      for (int h = 0; h < 4; ++h) s4[h] += __shfl_xor(s4[h], off);
    }
    float v = s4[0];
    if (hsel == 1) v = s4[1];
    if (hsel == 2) v = s4[2];
    if (hsel == 3) v = s4[3];
    sv[it] = v;
  }

  // per-wave max for head hsel over its 32 rows
  float m = -1e30f;
#pragma unroll
  for (int it = 0; it < 8; ++it) m = fmaxf(m, sv[it]);
  m = fmaxf(m, __shfl_xor(m, 16));
  m = fmaxf(m, __shfl_xor(m, 32));
  if (lane < 4) red[w][lane][0] = m;
  __syncthreads();

  // block max per head
  float M = -1e30f;
#pragma unroll
  for (int w2 = 0; w2 < 8; ++w2) M = fmaxf(M, red[w2][hsel][0]);

  // exp + per-wave sum
  float l = 0.f;
#pragma unroll
  for (int it = 0; it < 8; ++it) { sv[it] = __expf(sv[it] - M); l += sv[it]; }
  l += __shfl_xor(l, 16);
  l += __shfl_xor(l, 32);
  if (lane < 4) red[w][lane][1] = l;
  __syncthreads();

  // write (m, l) per (chunk, head)
  if (tid < 4) {
    float L = 0.f;
#pragma unroll
    for (int w2 = 0; w2 < 8; ++w2) L += red[w2][tid][1];
    size_t mi = ((size_t)blockIdx.x * 4 + tid) * 2;
    mlbuf[mi + 0] = M;
    mlbuf[mi + 1] = L;
  }

  // write unnormalized probs: one lane per (head, p) slot (ql < 4)
  if (ql < 4) {
    float* pp = pbuf + ((size_t)blockIdx.x * 4 + hsel) * 256;
#pragma unroll
    for (int it = 0; it < 8; ++it)
      pp[w * 32 + it * 4 + p] = sv[it];
  }
}

// ---------------------------------------------------------------------------
// K3b: PV pass — pure V streaming. block = (b, g, 256-row chunk), 512 thr =
// 8 waves; wave w owns rows [w*32,+32); half-wave owns a row, lane covers
// d=dq*4..+4. Probs staged in LDS (4KB, 1 barrier), then a fully-unrolled
// load+FMA loop (16 independent V loads in flight). LDS pacc combine.
// ---------------------------------------------------------------------------
__global__ __launch_bounds__(512) void attn_pv(
    const float* __restrict__ cache_v, const float* __restrict__ qkv,
    const float* __restrict__ pbuf, float* __restrict__ part) {
  __shared__ float ss[4 * 256];
  __shared__ float pacc[8][4][128];
  const int tid = threadIdx.x;
  const int w = tid >> 6, lane = tid & 63;
  const int c = blockIdx.x & (NACH - 1);
  const int g = (blockIdx.x >> 4) & 7;
  const int b = blockIdx.x >> 7;
  const int t0 = c * ACHUNK;

  // stage probs: [4 heads][256 rows]
  const float* pp = pbuf + (size_t)blockIdx.x * 1024;
  for (int i = tid; i < 1024; i += 512) ss[i] = pp[i];
  __syncthreads();

  const float* vbase = cache_v + ((size_t)b * 4096 * 8 + g) * 128;
  const float* xv    = qkv + b * QKV_COLS + 5120 + g * 128;
  const int h2 = lane >> 5, dq = lane & 31;

  f32x4 acc[4];
#pragma unroll
  for (int h = 0; h < 4; ++h) acc[h] = (f32x4)(0.f);

#pragma unroll
  for (int jj = 0; jj < 16; ++jj) {
    int lr = w * 32 + 2 * jj + h2;
    int t = t0 + lr;
    const float* vrow = (t == LASTPOS) ? xv : (vbase + (size_t)t * 1024);
    f32x4 vv = *(const f32x4*)(vrow + dq * 4);
    float p0 = ss[0 * 256 + lr];
    float p1 = ss[1 * 256 + lr];
    float p2 = ss[2 * 256 + lr];
    float p3 = ss[3 * 256 + lr];
    acc[0] += p0 * vv;
    acc[1] += p1 * vv;
    acc[2] += p2 * vv;
    acc[3] += p3 * vv;
  }
#pragma unroll
  for (int h = 0; h < 4; ++h) {
    acc[h][0] += __shfl_xor(acc[h][0], 32);
    acc[h][1] += __shfl_xor(acc[h][1], 32);
    acc[h][2] += __shfl_xor(acc[h][2], 32);
    acc[h][3] += __shfl_xor(acc[h][3], 32);
  }
  if (lane < 32) {
#pragma unroll
    for (int h = 0; h < 4; ++h)
      *(f32x4*)(&pacc[w][h][dq * 4]) = acc[h];
  }
  __syncthreads();

  // block combine: 512 threads = 4 heads x 128 d
  {
    int h = tid >> 7, d = tid & 127;
    float sum = 0.f;
#pragma unroll
    for (int w2 = 0; w2 < 8; ++w2) sum += pacc[w2][h][d];
    part[((size_t)blockIdx.x * 4 + h) * 128 + d] = sum;
  }
}

// ---------------------------------------------------------------------------
// K4: online-merge 16 chunk-partials per (b,g,h,d) -> attn_out. 65536 thr.
// ---------------------------------------------------------------------------
__global__ __launch_bounds__(256) void attn_combine(
    const float* __restrict__ part, const float* __restrict__ mlbuf,
    float* __restrict__ attn_out) {
  int t = blockIdx.x * 256 + threadIdx.x;   // 0..65535
  int d = t & 127, h = (t >> 7) & 3, g = (t >> 9) & 7, b = t >> 12;
  float M = -1e30f, num = 0.f, den = 0.f;
#pragma unroll 4
  for (int c = 0; c < NACH; ++c) {
    size_t blk = ((size_t)b << 7) | (g << 4) | c;   // matches blockIdx encode
    float mc = mlbuf[(blk * 4 + h) * 2 + 0];
    float lc = mlbuf[(blk * 4 + h) * 2 + 1];
    float Mn = fmaxf(M, mc);
    float fo = __expf(M - Mn);
    float fcur = __expf(mc - Mn);
    num = num * fo + fcur * part[(blk * 4 + h) * 128 + d];
    den = den * fo + fcur * lc;
    M = Mn;
  }
  attn_out[b * DIM + (g * 4 + h) * 128 + d] = num / den;
}

// ---------------------------------------------------------------------------
// K5a: wo partials. block: 256 thr, 2 cols/thread (512 cols); grid (8, 64).
// ---------------------------------------------------------------------------
__global__ __launch_bounds__(256) void out_projA(
    const float* __restrict__ attn, const float* __restrict__ wo,
    float* __restrict__ pw) {
  __shared__ float xs[16 * 64];
  const int tid = threadIdx.x;
  const int col = (blockIdx.x * 256 + tid) * 2;  // 0..4094
  const int kc = blockIdx.y;
  const int k0 = kc * 64;

  for (int i = tid; i < 1024; i += 256) {
    int b = i >> 6, k = i & 63;
    xs[i] = attn[b * DIM + k0 + k];
  }
  __syncthreads();

  const float* wp = wo + (size_t)k0 * 4096 + col;
  float acc0[16], acc1[16];
#pragma unroll
  for (int b = 0; b < 16; ++b) { acc0[b] = 0.f; acc1[b] = 0.f; }

#pragma unroll 2
  for (int k = 0; k < 64; k += 4) {
    float2 w0 = *(const float2*)(wp + (size_t)(k + 0) * 4096);
    float2 w1 = *(const float2*)(wp + (size_t)(k + 1) * 4096);
    float2 w2 = *(const float2*)(wp + (size_t)(k + 2) * 4096);
    float2 w3 = *(const float2*)(wp + (size_t)(k + 3) * 4096);
#pragma unroll
    for (int b = 0; b < 16; ++b) {
      float4 xb = *(const float4*)(&xs[b * 64 + k]);
      acc0[b] += xb.x * w0.x + xb.y * w1.x + xb.z * w2.x + xb.w * w3.x;
      acc1[b] += xb.x * w0.y + xb.y * w1.y + xb.z * w2.y + xb.w * w3.y;
    }
  }
#pragma unroll
  for (int b = 0; b < 16; ++b) {
    *(float2*)(&pw[((size_t)kc * 16 + b) * DIM + col]) = make_float2(acc0[b], acc1[b]);
  }
}

// ---------------------------------------------------------------------------
// K5b: reduce 64 wo partials -> d_out.
// ---------------------------------------------------------------------------
__global__ __launch_bounds__(256) void out_projB(
    const float* __restrict__ pw, float* __restrict__ out) {
  int t = blockIdx.x * 256 + threadIdx.x;  // 65536
  int b = t >> 12, col = t & 4095;
  float sum = 0.f;
#pragma unroll 8
  for (int kc = 0; kc < NKC; ++kc)
    sum += pw[((size_t)kc * 16 + b) * DIM + col];
  out[b * DIM + col] = sum;
}

// ---------------------------------------------------------------------------
extern "C" void kernel_launch(void* const* d_in, const int* in_sizes, int n_in,
                              void* d_out, int out_size, void* d_ws, size_t ws_size,
                              hipStream_t stream) {
  const float* x  = (const float*)d_in[0];
  const float* wq = (const float*)d_in[1];
  const float* wk = (const float*)d_in[2];
  const float* wv = (const float*)d_in[3];
  const float* wo = (const float*)d_in[4];
  const float* ck = (const float*)d_in[5];
  const float* cv = (const float*)d_in[6];
  const float* fc = (const float*)d_in[7];
  const float* fs = (const float*)d_in[8];

  float* ws_f  = (float*)d_ws;
  float* qkv   = ws_f + WS_QKV;
  float* attn  = ws_f + WS_ATTN;
  float* pbuf  = ws_f + WS_PBUF;
  float* mlbuf = ws_f + WS_MLBUF;
  float* part  = ws_f + WS_PART;
  float* pq    = ws_f + WS_PQ;
  float* pw    = ws_f + WS_PW;
  float* out   = (float*)d_out;

  qkv_projA<<<dim3(12, NKC), 256, 0, stream>>>(x, wq, wk, wv, pq);
  qkv_projB<<<192, 256, 0, stream>>>(pq, qkv, fc, fs);
  attn_score<<<16 * 8 * NACH, 512, 0, stream>>>(ck, qkv, pbuf, mlbuf);
  attn_pv<<<16 * 8 * NACH, 512, 0, stream>>>(cv, qkv, pbuf, part);
  attn_combine<<<256, 256, 0, stream>>>(part, mlbuf, attn);
  out_projA<<<dim3(8, NKC), 256, 0, stream>>>(attn, wo, pw);
  out_projB<<<256, 256, 0, stream>>>(pw, out);
}